// Round 3
// baseline (5041.732 us; speedup 1.0000x reference)
//
#include <hip/hip_runtime.h>
#include <hip/hip_fp16.h>
#include <cstdint>
#include <cstddef>

#define SEQ   128
#define BATCH 256
#define HDIM  1024
#define ODIM  128
#define NBLK  256

typedef _Float16 half_t;
typedef _Float16 half8 __attribute__((ext_vector_type(8)));
typedef float    f32x4 __attribute__((ext_vector_type(4)));

// dynamic LDS: B weights (f16, 128 KB) + P reduce buffer (fp32, 18 KB)
#define LDS_B_HALVES 65536                       // 2kh*16kk*4g*16u*4q*8
#define LDS_P_OFF    (LDS_B_HALVES * 2)          // 131072 B
#define LDS_BYTES    (LDS_P_OFF + 2 * 64 * 36 * 4)   // 149504 B (<160 KB/CU)

__device__ __forceinline__ float sigmoidf_(float z) {
    return 1.0f / (1.0f + __expf(-z));
}
__device__ __forceinline__ float tanhf_(float z) {
    z = fminf(fmaxf(z, -30.0f), 30.0f);
    float e = __expf(2.0f * z);
    return (e - 1.0f) / (e + 1.0f);
}

// Zero the per-step grid-barrier counters (d_ws is poisoned before each call).
__global__ __launch_bounds__(256) void lstm_init(int* __restrict__ bar) {
    bar[threadIdx.x] = 0;
}

// ---------------------------------------------------------------------------
// Persistent LSTM: 256 blocks (1/CU, forced by 146 KB LDS) x 256 threads.
// Block blk: bx=blk>>6 (64 batch rows), by=blk&63 (16 hidden units, 4 gates).
// Weights for the block's slice converted fp32->f16 into LDS ONCE; LDS is
// unaffected by the per-step coherence fences, so zero weight re-fetch.
// Waves: mh=w>>1 (batch half, 32 rows), kh=w&1 (K half, 512). A (h) is read
// exactly once per CU per step; kh=1 partials reduced into kh=0 via LDS P.
// c lives in registers (block-exclusive). h ping-pongs in global with a
// software grid barrier (per-step counter + agent-scope fences) each step.
// After step 127's barrier: fused projection + softmax (block = batch row).
// ---------------------------------------------------------------------------
__global__ __launch_bounds__(256, 1) void lstm_persist(
    const float* __restrict__ x,
    const float* __restrict__ Wfh, const float* __restrict__ Wih,
    const float* __restrict__ Wgh, const float* __restrict__ Woh,
    const float* __restrict__ Wfx, const float* __restrict__ Wix,
    const float* __restrict__ Wgx, const float* __restrict__ Wox,
    const float* __restrict__ bfx, const float* __restrict__ bix,
    const float* __restrict__ bgx, const float* __restrict__ box,
    const float* __restrict__ bfh, const float* __restrict__ bih,
    const float* __restrict__ bgh, const float* __restrict__ boh,
    const float* __restrict__ Wph, const float* __restrict__ bph,
    half_t* __restrict__ hbuf0, half_t* __restrict__ hbuf1,
    int* __restrict__ bar, float* __restrict__ out)
{
    extern __shared__ char smem[];
    half_t* Bs = (half_t*)smem;
    float*  P  = (float*)(smem + LDS_P_OFF);

    const int tid  = threadIdx.x;
    const int blk  = blockIdx.x;
    const int bx   = blk >> 6;
    const int by   = blk & 63;
    const int m0   = bx << 6;
    const int u0   = by << 4;

    const int w    = tid >> 6;
    const int lane = tid & 63;
    const int l15  = lane & 15;
    const int q    = lane >> 4;
    const int kh   = w & 1;          // K half
    const int mh   = w >> 1;         // batch half

    // ---- one-time: weight slice fp32 -> f16 into LDS, MFMA-frag order ----
    // chunk d -> (kh', kk, g, u-lane, q'): offset_halves = d*8;
    // element k = kh'*512 + kk*32 + q'*8 + j, row = u0 + ulane of gate g.
    {
        const float* Wh[4] = {Wfh, Wih, Wgh, Woh};
        for (int d = tid; d < 8192; d += 256) {
            const int qq = d & 3, ul = (d >> 2) & 15, g = (d >> 6) & 3;
            const int kk = (d >> 8) & 15, kh2 = d >> 12;
            const float* src = Wh[g] + (size_t)(u0 + ul) * HDIM
                             + kh2 * 512 + kk * 32 + qq * 8;
            const float4 v0 = *(const float4*)src;
            const float4 v1 = *(const float4*)(src + 4);
            half8 hv;
            hv[0] = (half_t)v0.x; hv[1] = (half_t)v0.y;
            hv[2] = (half_t)v0.z; hv[3] = (half_t)v0.w;
            hv[4] = (half_t)v1.x; hv[5] = (half_t)v1.y;
            hv[6] = (half_t)v1.z; hv[7] = (half_t)v1.w;
            *(half8*)(Bs + (size_t)d * 8) = hv;
        }
    }

    // ---- per-lane constants: fused bias (bx+bh) and x-weight per gate ----
    const int u = u0 + l15;
    const float bf = bfx[u] + bfh[u], bi = bix[u] + bih[u];
    const float bg = bgx[u] + bgh[u], bo = box[u] + boh[u];
    const float wf = Wfx[u], wi = Wix[u], wg = Wgx[u], wo = Wox[u];

    f32x4 creg[2] = {{0.f, 0.f, 0.f, 0.f}, {0.f, 0.f, 0.f, 0.f}};

    __syncthreads();   // LDS weights ready

    for (int t = 0; t < SEQ; ++t) {
        const half_t* hin  = (t & 1) ? hbuf1 : hbuf0;
        half_t*       hout = (t & 1) ? hbuf0 : hbuf1;

        f32x4 acc[2][4] = {};    // [batch r-tile][gate]

        if (t > 0) {
            // A frag: rows m0+32mh+16r+l15, k = kh*512 + kk*32 + q*8 (+j)
            const half_t* abase = hin + (size_t)(m0 + 32 * mh + l15) * HDIM
                                + kh * 512 + q * 8;
            half8 abuf[4][2];                      // depth-4 prefetch ring
#pragma unroll
            for (int d = 0; d < 4; ++d) {
                abuf[d][0] = *(const half8*)(abase + d * 32);
                abuf[d][1] = *(const half8*)(abase + 16 * HDIM + d * 32);
            }
#pragma unroll
            for (int kk = 0; kk < 16; ++kk) {
                const int sl = kk & 3;
                half8 bb[4];
#pragma unroll
                for (int g = 0; g < 4; ++g)
                    bb[g] = *(const half8*)(Bs +
                        ((size_t)((kh << 12) + (kk << 8) + (g << 6) + (l15 << 2) + q)) * 8);
#pragma unroll
                for (int g = 0; g < 4; ++g) {
                    acc[0][g] = __builtin_amdgcn_mfma_f32_16x16x32_f16(
                        abuf[sl][0], bb[g], acc[0][g], 0, 0, 0);
                    acc[1][g] = __builtin_amdgcn_mfma_f32_16x16x32_f16(
                        abuf[sl][1], bb[g], acc[1][g], 0, 0, 0);
                }
                if (kk < 12) {
                    abuf[sl][0] = *(const half8*)(abase + (kk + 4) * 32);
                    abuf[sl][1] = *(const half8*)(abase + 16 * HDIM + (kk + 4) * 32);
                }
            }
        }

        // ---- cross-wave K-reduce: kh=1 partials -> LDS P ----
        // C/D layout: col = lane&15 (u), row = q*4 + e (+16r within half)
        if (kh == 1) {
#pragma unroll
            for (int r = 0; r < 2; ++r)
#pragma unroll
                for (int g = 0; g < 4; ++g)
                    *(f32x4*)&P[(size_t)(mh * 64 + g * 16 + l15) * 36 + r * 16 + q * 4]
                        = acc[r][g];
        }
        __syncthreads();

        if (kh == 0) {
#pragma unroll
            for (int r = 0; r < 2; ++r) {
                const int b0r = m0 + 32 * mh + 16 * r + 4 * q;
                const float4 xv = *(const float4*)&x[t * BATCH + b0r];
                f32x4 zf = acc[r][0] + *(const f32x4*)&P[(size_t)(mh * 64 +  0 + l15) * 36 + r * 16 + q * 4];
                f32x4 zi = acc[r][1] + *(const f32x4*)&P[(size_t)(mh * 64 + 16 + l15) * 36 + r * 16 + q * 4];
                f32x4 zg = acc[r][2] + *(const f32x4*)&P[(size_t)(mh * 64 + 32 + l15) * 36 + r * 16 + q * 4];
                f32x4 zo = acc[r][3] + *(const f32x4*)&P[(size_t)(mh * 64 + 48 + l15) * 36 + r * 16 + q * 4];
#pragma unroll
                for (int e = 0; e < 4; ++e) {
                    const float xe = (e == 0) ? xv.x : (e == 1) ? xv.y
                                   : (e == 2) ? xv.z : xv.w;
                    const float fg = sigmoidf_(zf[e] + xe * wf + bf);
                    const float ig = sigmoidf_(zi[e] + xe * wi + bi);
                    const float gg = tanhf_  (zg[e] + xe * wg + bg);
                    const float og = sigmoidf_(zo[e] + xe * wo + bo);
                    const float cn = gg * ig + creg[r][e] * fg;
                    creg[r][e] = cn;
                    hout[((size_t)(b0r + e) << 10) + u] = (half_t)(tanhf_(cn) * og);
                }
            }
        }

        // ---- grid barrier: release h stores, arrive, spin, acquire ----
        __threadfence();
        __syncthreads();
        if (tid == 0) {
            __hip_atomic_fetch_add(&bar[t], 1, __ATOMIC_RELEASE,
                                   __HIP_MEMORY_SCOPE_AGENT);
            while (__hip_atomic_load(&bar[t], __ATOMIC_ACQUIRE,
                                     __HIP_MEMORY_SCOPE_AGENT) < NBLK)
                __builtin_amdgcn_s_sleep(1);
        }
        __syncthreads();
    }

    // ---- fused projection + softmax: block = batch row blk ----
    // (last barrier made final h (hbuf0) globally visible)
    float* sm     = (float*)smem;     // reuse LDS: hrow[1024] psum[256] logits[128]
    float* hrow   = sm;
    float* psum   = sm + 1024;
    float* logits = sm + 1280;
    const half_t* hf = hbuf0 + ((size_t)blk << 10);

    for (int k = tid; k < HDIM; k += 256) hrow[k] = (float)hf[k];
    __syncthreads();

    const int j = tid & 127, hlf = tid >> 7;
    const float4* wp = (const float4*)(Wph + (size_t)j * HDIM + hlf * 512);
    const float4* hp = (const float4*)(hrow + hlf * 512);
    float s = 0.0f;
#pragma unroll 8
    for (int k4 = 0; k4 < 128; ++k4) {
        const float4 wv = wp[k4];
        const float4 hv = hp[k4];
        s += wv.x * hv.x + wv.y * hv.y + wv.z * hv.z + wv.w * hv.w;
    }
    psum[tid] = s;
    __syncthreads();
    if (tid < ODIM) logits[tid] = psum[tid] + psum[tid + 128] + bph[tid];
    __syncthreads();
    if (tid < ODIM) {
        float mx = -1e30f;
        for (int i = 0; i < ODIM; ++i) mx = fmaxf(mx, logits[i]);
        psum[tid] = __expf(logits[tid] - mx);
    }
    __syncthreads();
    if (tid < ODIM) {
        float ssum = 0.0f;
        for (int i = 0; i < ODIM; ++i) ssum += psum[i];
        out[blk * ODIM + tid] = psum[tid] / ssum;
    }
}

// ---------------------------------------------------------------------------
extern "C" void kernel_launch(void* const* d_in, const int* in_sizes, int n_in,
                              void* d_out, int out_size, void* d_ws, size_t ws_size,
                              hipStream_t stream) {
    const float* x   = (const float*)d_in[0];
    const float* Wfx = (const float*)d_in[1];
    const float* bfx = (const float*)d_in[2];
    const float* Wfh = (const float*)d_in[3];
    const float* bfh = (const float*)d_in[4];
    const float* Wix = (const float*)d_in[5];
    const float* bix = (const float*)d_in[6];
    const float* Wih = (const float*)d_in[7];
    const float* bih = (const float*)d_in[8];
    const float* Wgx = (const float*)d_in[9];
    const float* bgx = (const float*)d_in[10];
    const float* Wgh = (const float*)d_in[11];
    const float* bgh = (const float*)d_in[12];
    const float* Wox = (const float*)d_in[13];
    const float* box = (const float*)d_in[14];
    const float* Woh = (const float*)d_in[15];
    const float* boh = (const float*)d_in[16];
    const float* Wph = (const float*)d_in[17];
    const float* bph = (const float*)d_in[18];
    float* outp = (float*)d_out;

    char* ws = (char*)d_ws;
    half_t* h0  = (half_t*)ws;                 // 512 KB
    half_t* h1  = (half_t*)(ws + 524288);      // 512 KB
    int*    bar = (int*)   (ws + 1048576);     // 1 KB (256 counters)

    lstm_init<<<1, 256, 0, stream>>>(bar);

    (void)hipFuncSetAttribute((const void*)lstm_persist,
                              hipFuncAttributeMaxDynamicSharedMemorySize,
                              LDS_BYTES);

    void* args[] = {
        (void*)&x,
        (void*)&Wfh, (void*)&Wih, (void*)&Wgh, (void*)&Woh,
        (void*)&Wfx, (void*)&Wix, (void*)&Wgx, (void*)&Wox,
        (void*)&bfx, (void*)&bix, (void*)&bgx, (void*)&box,
        (void*)&bfh, (void*)&bih, (void*)&bgh, (void*)&boh,
        (void*)&Wph, (void*)&bph,
        (void*)&h0, (void*)&h1, (void*)&bar, (void*)&outp
    };
    (void)hipLaunchCooperativeKernel((const void*)lstm_persist,
                                     dim3(NBLK), dim3(256),
                                     args, LDS_BYTES, stream);
}

// Round 4
// 1833.592 us; speedup vs baseline: 2.7496x; 2.7496x over previous
//
#include <hip/hip_runtime.h>
#include <hip/hip_fp16.h>
#include <cstdint>
#include <cstddef>

#define SEQ   128
#define BATCH 256
#define HDIM  1024
#define ODIM  128
#define NBLK  256

typedef _Float16 half_t;
typedef _Float16 half8 __attribute__((ext_vector_type(8)));
typedef float    f32x4 __attribute__((ext_vector_type(4)));
typedef unsigned long long u64;

// dynamic LDS: B weights (f16, 128 KB) + P reduce buffer (fp32, 18 KB)
#define LDS_B_HALVES 65536
#define LDS_P_OFF    (LDS_B_HALVES * 2)
#define LDS_BYTES    (LDS_P_OFF + 2 * 64 * 36 * 4)   // 149504 B

// workspace layout: 129 h ping buffers (fresh buffer per step => no stale L2
// lines anywhere => barrier needs no acquire/invalidate), then flags.
#define HBUF_BYTES   524288                      // 256*1024*2
#define FLAGS_OFF    ((size_t)129 * HBUF_BYTES)  // 67,633,152
// flags[t][group][64] bytes = 128*4*64 = 32 KB

__device__ __forceinline__ float sigmoidf_(float z) {
    return 1.0f / (1.0f + __expf(-z));
}
__device__ __forceinline__ float tanhf_(float z) {
    z = fminf(fmaxf(z, -30.0f), 30.0f);
    float e = __expf(2.0f * z);
    return (e - 1.0f) / (e + 1.0f);
}

// Zero the barrier flags (ws is re-poisoned to 0xAA before every timed call).
__global__ __launch_bounds__(256) void lstm_init(int4* __restrict__ flags4) {
#pragma unroll
    for (int i = 0; i < 8; ++i) {
        int4 z; z.x = z.y = z.z = z.w = 0;
        flags4[threadIdx.x * 8 + i] = z;
    }
}

// ---------------------------------------------------------------------------
// Persistent LSTM: 256 blocks (1/CU via 146 KB LDS) x 256 threads.
// Group g = blk&3 owns batch rows [64g, 64g+64) -- a fully independent
// recurrence chain (batch rows never interact until the per-row projection,
// which is also mapped group-locally). by = blk>>2 owns 16 hidden units
// (all 4 gates), weights f16 in LDS loaded once.
// Per-step sync: ONE release byte-store per block (emits waitcnt+buffer_wbl2,
// pushing the block's 2 KB of h to LLC) + tid0 polling the group's 64 flags
// via 8 relaxed u64 atomic loads (bypass L2, no invalidate). Fresh h buffer
// per step makes acquire/inv unnecessary: no stale copy can exist.
// ---------------------------------------------------------------------------
__global__ __launch_bounds__(256, 1) void lstm_persist(
    const float* __restrict__ x,
    const float* __restrict__ Wfh, const float* __restrict__ Wih,
    const float* __restrict__ Wgh, const float* __restrict__ Woh,
    const float* __restrict__ Wfx, const float* __restrict__ Wix,
    const float* __restrict__ Wgx, const float* __restrict__ Wox,
    const float* __restrict__ bfx, const float* __restrict__ bix,
    const float* __restrict__ bgx, const float* __restrict__ box,
    const float* __restrict__ bfh, const float* __restrict__ bih,
    const float* __restrict__ bgh, const float* __restrict__ boh,
    const float* __restrict__ Wph, const float* __restrict__ bph,
    char* __restrict__ wsbase, float* __restrict__ out)
{
    extern __shared__ char smem[];
    half_t* Bs = (half_t*)smem;
    float*  P  = (float*)(smem + LDS_P_OFF);
    unsigned char* flags = (unsigned char*)(wsbase + FLAGS_OFF);

    const int tid  = threadIdx.x;
    const int blk  = blockIdx.x;
    const int grp  = blk & 3;        // batch group (64 rows)
    const int by   = blk >> 2;       // u-tile within group (16 units)
    const int m0   = grp << 6;
    const int u0   = by << 4;

    const int w    = tid >> 6;
    const int lane = tid & 63;
    const int l15  = lane & 15;
    const int q    = lane >> 4;
    const int kh   = w & 1;          // K half
    const int mh   = w >> 1;         // batch half (32 rows)

    // ---- one-time: weight slice fp32 -> f16 into LDS, MFMA-frag order ----
    {
        const float* Wh[4] = {Wfh, Wih, Wgh, Woh};
        for (int d = tid; d < 8192; d += 256) {
            const int qq = d & 3, ul = (d >> 2) & 15, g = (d >> 6) & 3;
            const int kk = (d >> 8) & 15, kh2 = d >> 12;
            const float* src = Wh[g] + (size_t)(u0 + ul) * HDIM
                             + kh2 * 512 + kk * 32 + qq * 8;
            const float4 v0 = *(const float4*)src;
            const float4 v1 = *(const float4*)(src + 4);
            half8 hv;
            hv[0] = (half_t)v0.x; hv[1] = (half_t)v0.y;
            hv[2] = (half_t)v0.z; hv[3] = (half_t)v0.w;
            hv[4] = (half_t)v1.x; hv[5] = (half_t)v1.y;
            hv[6] = (half_t)v1.z; hv[7] = (half_t)v1.w;
            *(half8*)(Bs + (size_t)d * 8) = hv;
        }
    }

    // ---- per-lane constants ----
    const int u = u0 + l15;
    const float bf = bfx[u] + bfh[u], bi = bix[u] + bih[u];
    const float bg = bgx[u] + bgh[u], bo = box[u] + boh[u];
    const float wf = Wfx[u], wi = Wix[u], wg = Wgx[u], wo = Wox[u];

    f32x4 creg[2] = {{0.f, 0.f, 0.f, 0.f}, {0.f, 0.f, 0.f, 0.f}};

    __syncthreads();   // LDS weights ready

    for (int t = 0; t < SEQ; ++t) {
        const half_t* hin  = (const half_t*)(wsbase + (size_t)t * HBUF_BYTES);
        half_t*       hout = (half_t*)(wsbase + (size_t)(t + 1) * HBUF_BYTES);

        f32x4 acc[2][4] = {};

        if (t > 0) {
            const half_t* abase = hin + (size_t)(m0 + 32 * mh + l15) * HDIM
                                + kh * 512 + q * 8;
            half8 abuf[4][2];
#pragma unroll
            for (int d = 0; d < 4; ++d) {
                abuf[d][0] = *(const half8*)(abase + d * 32);
                abuf[d][1] = *(const half8*)(abase + 16 * HDIM + d * 32);
            }
#pragma unroll
            for (int kk = 0; kk < 16; ++kk) {
                const int sl = kk & 3;
                half8 bb[4];
#pragma unroll
                for (int g = 0; g < 4; ++g)
                    bb[g] = *(const half8*)(Bs +
                        ((size_t)((kh << 12) + (kk << 8) + (g << 6) + (l15 << 2) + q)) * 8);
#pragma unroll
                for (int g = 0; g < 4; ++g) {
                    acc[0][g] = __builtin_amdgcn_mfma_f32_16x16x32_f16(
                        abuf[sl][0], bb[g], acc[0][g], 0, 0, 0);
                    acc[1][g] = __builtin_amdgcn_mfma_f32_16x16x32_f16(
                        abuf[sl][1], bb[g], acc[1][g], 0, 0, 0);
                }
                if (kk < 12) {
                    abuf[sl][0] = *(const half8*)(abase + (kk + 4) * 32);
                    abuf[sl][1] = *(const half8*)(abase + 16 * HDIM + (kk + 4) * 32);
                }
            }
        }

        // ---- cross-wave K-reduce: kh=1 partials -> LDS P ----
        if (kh == 1) {
#pragma unroll
            for (int r = 0; r < 2; ++r)
#pragma unroll
                for (int g = 0; g < 4; ++g)
                    *(f32x4*)&P[(size_t)(mh * 64 + g * 16 + l15) * 36 + r * 16 + q * 4]
                        = acc[r][g];
        }
        __syncthreads();

        if (kh == 0) {
#pragma unroll
            for (int r = 0; r < 2; ++r) {
                const int b0r = m0 + 32 * mh + 16 * r + 4 * q;
                const float4 xv = *(const float4*)&x[t * BATCH + b0r];
                f32x4 zf = acc[r][0] + *(const f32x4*)&P[(size_t)(mh * 64 +  0 + l15) * 36 + r * 16 + q * 4];
                f32x4 zi = acc[r][1] + *(const f32x4*)&P[(size_t)(mh * 64 + 16 + l15) * 36 + r * 16 + q * 4];
                f32x4 zg = acc[r][2] + *(const f32x4*)&P[(size_t)(mh * 64 + 32 + l15) * 36 + r * 16 + q * 4];
                f32x4 zo = acc[r][3] + *(const f32x4*)&P[(size_t)(mh * 64 + 48 + l15) * 36 + r * 16 + q * 4];
#pragma unroll
                for (int e = 0; e < 4; ++e) {
                    const float xe = (e == 0) ? xv.x : (e == 1) ? xv.y
                                   : (e == 2) ? xv.z : xv.w;
                    const float fg = sigmoidf_(zf[e] + xe * wf + bf);
                    const float ig = sigmoidf_(zi[e] + xe * wi + bi);
                    const float gg = tanhf_  (zg[e] + xe * wg + bg);
                    const float og = sigmoidf_(zo[e] + xe * wo + bo);
                    const float cn = gg * ig + creg[r][e] * fg;
                    creg[r][e] = cn;
                    hout[((size_t)(b0r + e) << 10) + u] = (half_t)(tanhf_(cn) * og);
                }
            }
        }

        // ---- group barrier: release flag store + relaxed flag poll ----
        __syncthreads();   // all threads' h stores drained (vmcnt) & visible in L2
        if (tid == 0) {
            // RELEASE at agent scope: s_waitcnt + buffer_wbl2 + byte store (sc1)
            __hip_atomic_store(&flags[(t << 8) + (grp << 6) + by],
                               (unsigned char)1,
                               __ATOMIC_RELEASE, __HIP_MEMORY_SCOPE_AGENT);
            u64* pf = (u64*)&flags[(t << 8) + (grp << 6)];
            const u64 FULL = 0x0101010101010101ull;
            for (;;) {
                int ok = 1;
#pragma unroll
                for (int i = 0; i < 8; ++i)
                    ok &= (__hip_atomic_load(&pf[i], __ATOMIC_RELAXED,
                                             __HIP_MEMORY_SCOPE_AGENT) == FULL);
                if (ok) break;
                __builtin_amdgcn_s_sleep(1);
            }
        }
        asm volatile("" ::: "memory");   // compiler barrier (no hoisting)
        __syncthreads();
    }

    // ---- fused projection + softmax, group-local row: r = 64*grp + by ----
    const int row = (grp << 6) + by;
    float* sm     = (float*)smem;
    float* hrow   = sm;
    float* psum   = sm + 1024;
    float* logits = sm + 1280;
    const half_t* hf = (const half_t*)(wsbase + (size_t)SEQ * HBUF_BYTES)
                     + ((size_t)row << 10);

    for (int k = tid; k < HDIM; k += 256) hrow[k] = (float)hf[k];
    __syncthreads();

    const int j = tid & 127, hlf = tid >> 7;
    const float4* wp = (const float4*)(Wph + (size_t)j * HDIM + hlf * 512);
    const float4* hp = (const float4*)(hrow + hlf * 512);
    float s = 0.0f;
#pragma unroll 8
    for (int k4 = 0; k4 < 128; ++k4) {
        const float4 wv = wp[k4];
        const float4 hv = hp[k4];
        s += wv.x * hv.x + wv.y * hv.y + wv.z * hv.z + wv.w * hv.w;
    }
    psum[tid] = s;
    __syncthreads();
    if (tid < ODIM) logits[tid] = psum[tid] + psum[tid + 128] + bph[tid];
    __syncthreads();
    if (tid < ODIM) {
        float mx = -1e30f;
        for (int i = 0; i < ODIM; ++i) mx = fmaxf(mx, logits[i]);
        psum[tid] = __expf(logits[tid] - mx);
    }
    __syncthreads();
    if (tid < ODIM) {
        float ssum = 0.0f;
        for (int i = 0; i < ODIM; ++i) ssum += psum[i];
        out[row * ODIM + tid] = psum[tid] / ssum;
    }
}

// ---------------------------------------------------------------------------
extern "C" void kernel_launch(void* const* d_in, const int* in_sizes, int n_in,
                              void* d_out, int out_size, void* d_ws, size_t ws_size,
                              hipStream_t stream) {
    const float* x   = (const float*)d_in[0];
    const float* Wfx = (const float*)d_in[1];
    const float* bfx = (const float*)d_in[2];
    const float* Wfh = (const float*)d_in[3];
    const float* bfh = (const float*)d_in[4];
    const float* Wix = (const float*)d_in[5];
    const float* bix = (const float*)d_in[6];
    const float* Wih = (const float*)d_in[7];
    const float* bih = (const float*)d_in[8];
    const float* Wgx = (const float*)d_in[9];
    const float* bgx = (const float*)d_in[10];
    const float* Wgh = (const float*)d_in[11];
    const float* bgh = (const float*)d_in[12];
    const float* Wox = (const float*)d_in[13];
    const float* box = (const float*)d_in[14];
    const float* Woh = (const float*)d_in[15];
    const float* boh = (const float*)d_in[16];
    const float* Wph = (const float*)d_in[17];
    const float* bph = (const float*)d_in[18];
    float* outp = (float*)d_out;

    char* ws = (char*)d_ws;
    int4* flags4 = (int4*)(ws + FLAGS_OFF);

    lstm_init<<<1, 256, 0, stream>>>(flags4);

    (void)hipFuncSetAttribute((const void*)lstm_persist,
                              hipFuncAttributeMaxDynamicSharedMemorySize,
                              LDS_BYTES);

    void* args[] = {
        (void*)&x,
        (void*)&Wfh, (void*)&Wih, (void*)&Wgh, (void*)&Woh,
        (void*)&Wfx, (void*)&Wix, (void*)&Wgx, (void*)&Wox,
        (void*)&bfx, (void*)&bix, (void*)&bgx, (void*)&box,
        (void*)&bfh, (void*)&bih, (void*)&bgh, (void*)&boh,
        (void*)&Wph, (void*)&bph,
        (void*)&ws, (void*)&outp
    };
    (void)hipLaunchCooperativeKernel((const void*)lstm_persist,
                                     dim3(NBLK), dim3(256),
                                     args, LDS_BYTES, stream);
}

// Round 5
// 1328.255 us; speedup vs baseline: 3.7958x; 1.3805x over previous
//
#include <hip/hip_runtime.h>
#include <hip/hip_fp16.h>
#include <cstdint>
#include <cstddef>

#define SEQ   128
#define BATCH 256
#define HDIM  1024
#define ODIM  128
#define NBLK  256

typedef _Float16 half_t;
typedef _Float16 half8 __attribute__((ext_vector_type(8)));
typedef float    f32x4 __attribute__((ext_vector_type(4)));
typedef unsigned long long u64;

// dynamic LDS: B weights (128 KB) + P reduce (18 KB) + Hs h-out staging (2 KB)
#define LDS_P_OFF    131072
#define LDS_HS_OFF   (LDS_P_OFF + 2 * 64 * 36 * 4)       // 149504
#define LDS_BYTES    (LDS_HS_OFF + 64 * 16 * 2)          // 151552 (<160 KiB)

// ws: 129 fresh h buffers (no stale-cache hazard => no acquire/invalidate
// needed anywhere), then int flags[128][4][64] (128 KB).
#define HBUF_BYTES   524288
#define FLAGS_OFF    ((size_t)129 * HBUF_BYTES)          // 67,633,152

__device__ __forceinline__ float sigmoidf_(float z) {
    return 1.0f / (1.0f + __expf(-z));
}
__device__ __forceinline__ float tanhf_(float z) {
    z = fminf(fmaxf(z, -30.0f), 30.0f);
    float e = __expf(2.0f * z);
    return (e - 1.0f) / (e + 1.0f);
}

// Zero the 128 KB flag array (ws re-poisoned to 0xAA before every call).
__global__ __launch_bounds__(256) void lstm_init(int* __restrict__ flags) {
    flags[blockIdx.x * 256 + threadIdx.x] = 0;
}

// ---------------------------------------------------------------------------
// Persistent LSTM: 256 blocks (1/CU via 148 KB LDS) x 256 threads.
// Group grp = blk&3 owns batch rows [64*grp, 64*grp+64) -- an independent
// recurrence chain; sync domain = 64 blocks. by = blk>>2 owns 16 hidden
// units x 4 gates; weights f16 in LDS (loaded once, conflict-free layout).
// h is stored WRITE-THROUGH (agent-scope relaxed atomic stores, sc1 -> LLC,
// never dirty in L2) so the per-step barrier needs NO wbl2/inv: per-wave
// s_waitcnt vmcnt(0) + block barrier + one relaxed flag store; wave0 polls
// the group's 64 int flags (1 coalesced load + __all per sweep).
// c lives in registers. Fresh h buffer per step kills all stale-cache paths.
// ---------------------------------------------------------------------------
__global__ __launch_bounds__(256, 1) void lstm_persist(
    const float* __restrict__ x,
    const float* __restrict__ Wfh, const float* __restrict__ Wih,
    const float* __restrict__ Wgh, const float* __restrict__ Woh,
    const float* __restrict__ Wfx, const float* __restrict__ Wix,
    const float* __restrict__ Wgx, const float* __restrict__ Wox,
    const float* __restrict__ bfx, const float* __restrict__ bix,
    const float* __restrict__ bgx, const float* __restrict__ box,
    const float* __restrict__ bfh, const float* __restrict__ bih,
    const float* __restrict__ bgh, const float* __restrict__ boh,
    const float* __restrict__ Wph, const float* __restrict__ bph,
    char* __restrict__ wsbase, float* __restrict__ out)
{
    extern __shared__ char smem[];
    half_t* Bs = (half_t*)smem;
    float*  P  = (float*)(smem + LDS_P_OFF);
    half_t* Hs = (half_t*)(smem + LDS_HS_OFF);
    int* flags = (int*)(wsbase + FLAGS_OFF);

    const int tid  = threadIdx.x;
    const int blk  = blockIdx.x;
    const int grp  = blk & 3;        // batch group (64 rows)
    const int by   = blk >> 2;       // u-tile within group (16 units)
    const int m0   = grp << 6;
    const int u0   = by << 4;

    const int w    = tid >> 6;
    const int lane = tid & 63;
    const int l15  = lane & 15;
    const int q    = lane >> 4;
    const int kh   = w & 1;          // K half (512)
    const int mh   = w >> 1;         // batch half (32 rows)

    // ---- one-time: weight slice fp32 -> f16 into LDS ----
    // slot d: l15=d&15 (unit), q'=(d>>4)&3, g=(d>>6)&3, kk=(d>>8)&15, kh'=d>>12
    // read addr per instr = contiguous 1024 B across (q,l15) -> conflict-free.
    {
        const float* Wh[4] = {Wfh, Wih, Wgh, Woh};
        for (int d = tid; d < 8192; d += 256) {
            const int ul = d & 15, qq = (d >> 4) & 3, g = (d >> 6) & 3;
            const int kk = (d >> 8) & 15, kh2 = d >> 12;
            const float* src = Wh[g] + (size_t)(u0 + ul) * HDIM
                             + kh2 * 512 + kk * 32 + qq * 8;
            const float4 v0 = *(const float4*)src;
            const float4 v1 = *(const float4*)(src + 4);
            half8 hv;
            hv[0] = (half_t)v0.x; hv[1] = (half_t)v0.y;
            hv[2] = (half_t)v0.z; hv[3] = (half_t)v0.w;
            hv[4] = (half_t)v1.x; hv[5] = (half_t)v1.y;
            hv[6] = (half_t)v1.z; hv[7] = (half_t)v1.w;
            *(half8*)(Bs + (size_t)d * 8) = hv;
        }
    }

    // ---- per-lane constants ----
    const int u = u0 + l15;
    const float bf = bfx[u] + bfh[u], bi = bix[u] + bih[u];
    const float bg = bgx[u] + bgh[u], bo = box[u] + boh[u];
    const float wf = Wfx[u], wi = Wix[u], wg = Wgx[u], wo = Wox[u];

    f32x4 creg[2] = {{0.f, 0.f, 0.f, 0.f}, {0.f, 0.f, 0.f, 0.f}};

    __syncthreads();   // LDS weights ready

    for (int t = 0; t < SEQ; ++t) {
        const half_t* hin  = (const half_t*)(wsbase + (size_t)t * HBUF_BYTES);
        half_t*       hout = (half_t*)(wsbase + (size_t)(t + 1) * HBUF_BYTES);

        f32x4 acc[2][4] = {};

        if (t > 0) {
            // Full A preload: 32 b128 loads in flight (h comes from LLC).
            const half_t* abase = hin + (size_t)(m0 + 32 * mh + l15) * HDIM
                                + kh * 512 + q * 8;
            half8 a0[16], a1[16];
#pragma unroll
            for (int kk = 0; kk < 16; ++kk) {
                a0[kk] = *(const half8*)(abase + kk * 32);
                a1[kk] = *(const half8*)(abase + 16 * HDIM + kk * 32);
            }
#pragma unroll
            for (int kk = 0; kk < 16; ++kk) {
                half8 bb[4];
#pragma unroll
                for (int g = 0; g < 4; ++g)
                    bb[g] = *(const half8*)(Bs +
                        ((size_t)((kh << 12) + (kk << 8) + (g << 6) + (q << 4) + l15)) * 8);
#pragma unroll
                for (int g = 0; g < 4; ++g) {
                    acc[0][g] = __builtin_amdgcn_mfma_f32_16x16x32_f16(
                        a0[kk], bb[g], acc[0][g], 0, 0, 0);
                    acc[1][g] = __builtin_amdgcn_mfma_f32_16x16x32_f16(
                        a1[kk], bb[g], acc[1][g], 0, 0, 0);
                }
            }
        }

        // ---- cross-wave K-reduce: kh=1 partials -> LDS P ----
        if (kh == 1) {
#pragma unroll
            for (int r = 0; r < 2; ++r)
#pragma unroll
                for (int g = 0; g < 4; ++g)
                    *(f32x4*)&P[(size_t)(mh * 64 + g * 16 + l15) * 36 + r * 16 + q * 4]
                        = acc[r][g];
        }
        __syncthreads();

        if (kh == 0) {
#pragma unroll
            for (int r = 0; r < 2; ++r) {
                const int lr0 = 32 * mh + 16 * r + 4 * q;     // local row base
                const float4 xv = *(const float4*)&x[t * BATCH + m0 + lr0];
                f32x4 zf = acc[r][0] + *(const f32x4*)&P[(size_t)(mh * 64 +  0 + l15) * 36 + r * 16 + q * 4];
                f32x4 zi = acc[r][1] + *(const f32x4*)&P[(size_t)(mh * 64 + 16 + l15) * 36 + r * 16 + q * 4];
                f32x4 zg = acc[r][2] + *(const f32x4*)&P[(size_t)(mh * 64 + 32 + l15) * 36 + r * 16 + q * 4];
                f32x4 zo = acc[r][3] + *(const f32x4*)&P[(size_t)(mh * 64 + 48 + l15) * 36 + r * 16 + q * 4];
#pragma unroll
                for (int e = 0; e < 4; ++e) {
                    const float xe = (e == 0) ? xv.x : (e == 1) ? xv.y
                                   : (e == 2) ? xv.z : xv.w;
                    const float fg = sigmoidf_(zf[e] + xe * wf + bf);
                    const float ig = sigmoidf_(zi[e] + xe * wi + bi);
                    const float gg = tanhf_  (zg[e] + xe * wg + bg);
                    const float og = sigmoidf_(zo[e] + xe * wo + bo);
                    const float cn = gg * ig + creg[r][e] * fg;
                    creg[r][e] = cn;
                    Hs[(lr0 + e) * 16 + l15] = (half_t)(tanhf_(cn) * og);
                }
            }
        }
        __syncthreads();   // Hs complete

        // ---- coalesced write-through h store: 1 x u64 per thread (sc1) ----
        {
            const int lr = tid >> 2, p = tid & 3;
            const u64 v = *(const u64*)&Hs[lr * 16 + p * 4];
            u64* dst = (u64*)(hout + (size_t)(m0 + lr) * HDIM + u0 + p * 4);
            __hip_atomic_store(dst, v, __ATOMIC_RELAXED, __HIP_MEMORY_SCOPE_AGENT);
        }
        asm volatile("s_waitcnt vmcnt(0)" ::: "memory");  // per-wave: h at LLC
        __syncthreads();                                   // all waves drained

        // ---- flag + poll (no fences, no wbl2/inv anywhere) ----
        if (tid == 0)
            __hip_atomic_store(&flags[(t << 8) + (grp << 6) + by], 1,
                               __ATOMIC_RELAXED, __HIP_MEMORY_SCOPE_AGENT);
        if (w == 0) {
            const int* pf = &flags[(t << 8) + (grp << 6)];
            for (;;) {
                const int v = __hip_atomic_load(&pf[lane], __ATOMIC_RELAXED,
                                                __HIP_MEMORY_SCOPE_AGENT);
                if (__all(v == 1)) break;
                __builtin_amdgcn_s_sleep(1);
            }
        }
        asm volatile("" ::: "memory");
        __syncthreads();
    }

    // ---- fused projection + softmax, group-local row = 64*grp + by ----
    const int row = (grp << 6) + by;
    float* sm     = (float*)smem;
    float* hrow   = sm;
    float* psum   = sm + 1024;
    float* logits = sm + 1280;
    const half_t* hf = (const half_t*)(wsbase + (size_t)SEQ * HBUF_BYTES)
                     + ((size_t)row << 10);

    for (int k = tid; k < HDIM; k += 256) hrow[k] = (float)hf[k];
    __syncthreads();

    const int j = tid & 127, hlf = tid >> 7;
    const float4* wp = (const float4*)(Wph + (size_t)j * HDIM + hlf * 512);
    const float4* hp = (const float4*)(hrow + hlf * 512);
    float s = 0.0f;
#pragma unroll 8
    for (int k4 = 0; k4 < 128; ++k4) {
        const float4 wv = wp[k4];
        const float4 hv = hp[k4];
        s += wv.x * hv.x + wv.y * hv.y + wv.z * hv.z + wv.w * hv.w;
    }
    psum[tid] = s;
    __syncthreads();
    if (tid < ODIM) logits[tid] = psum[tid] + psum[tid + 128] + bph[tid];
    __syncthreads();
    if (tid < ODIM) {
        float mx = -1e30f;
        for (int i = 0; i < ODIM; ++i) mx = fmaxf(mx, logits[i]);
        psum[tid] = __expf(logits[tid] - mx);
    }
    __syncthreads();
    if (tid < ODIM) {
        float ssum = 0.0f;
        for (int i = 0; i < ODIM; ++i) ssum += psum[i];
        out[row * ODIM + tid] = psum[tid] / ssum;
    }
}

// ---------------------------------------------------------------------------
extern "C" void kernel_launch(void* const* d_in, const int* in_sizes, int n_in,
                              void* d_out, int out_size, void* d_ws, size_t ws_size,
                              hipStream_t stream) {
    const float* x   = (const float*)d_in[0];
    const float* Wfx = (const float*)d_in[1];
    const float* bfx = (const float*)d_in[2];
    const float* Wfh = (const float*)d_in[3];
    const float* bfh = (const float*)d_in[4];
    const float* Wix = (const float*)d_in[5];
    const float* bix = (const float*)d_in[6];
    const float* Wih = (const float*)d_in[7];
    const float* bih = (const float*)d_in[8];
    const float* Wgx = (const float*)d_in[9];
    const float* bgx = (const float*)d_in[10];
    const float* Wgh = (const float*)d_in[11];
    const float* bgh = (const float*)d_in[12];
    const float* Wox = (const float*)d_in[13];
    const float* box = (const float*)d_in[14];
    const float* Woh = (const float*)d_in[15];
    const float* boh = (const float*)d_in[16];
    const float* Wph = (const float*)d_in[17];
    const float* bph = (const float*)d_in[18];
    float* outp = (float*)d_out;

    char* ws = (char*)d_ws;
    int* flags = (int*)(ws + FLAGS_OFF);

    lstm_init<<<128, 256, 0, stream>>>(flags);   // zero 128 KB of flags

    (void)hipFuncSetAttribute((const void*)lstm_persist,
                              hipFuncAttributeMaxDynamicSharedMemorySize,
                              LDS_BYTES);

    void* args[] = {
        (void*)&x,
        (void*)&Wfh, (void*)&Wih, (void*)&Wgh, (void*)&Woh,
        (void*)&Wfx, (void*)&Wix, (void*)&Wgx, (void*)&Wox,
        (void*)&bfx, (void*)&bix, (void*)&bgx, (void*)&box,
        (void*)&bfh, (void*)&bih, (void*)&bgh, (void*)&boh,
        (void*)&Wph, (void*)&bph,
        (void*)&ws, (void*)&outp
    };
    (void)hipLaunchCooperativeKernel((const void*)lstm_persist,
                                     dim3(NBLK), dim3(256),
                                     args, LDS_BYTES, stream);
}